// Round 1
// baseline (186.689 us; speedup 1.0000x reference)
//
#include <hip/hip_runtime.h>
#include <hip/hip_cooperative_groups.h>
#include <math.h>

// Problem: TOTAL=16M fp32 y/mu/std; idx int32 [200,100].
// q[i] = sum_j ((y[idx]-mu[idx])/std[idx])^2 ; out = KL(N(mean(q),var(q,ddof=1)) || N(K, 2K)).
// Latency-bound random-gather + tiny reduction.
//
// R1: fuse the two kernels into ONE cooperative launch (200 blocks x 256 thr).
//   Phase 1: block i computes q[i] (100 gathers, wave reduce) -> d_ws
//   grid.sync()  (runtime-initialized barrier; no workspace counter init needed,
//                 which matters because d_ws is poisoned each iteration)
//   Phase 2: block 0 runs the exact 256-thread finalize from the previous version
//            (bitwise-identical arithmetic -> absmax should stay 0.0).
// Saves one kernel dispatch + the k1->k2 dependency bubble; the ~40us
// fillBufferAligned seen in rocprof is the harness ws re-poison (not ours).

#define NUM_SAMPLES 200
#define KDOF 100

namespace cg = cooperative_groups;

__device__ __forceinline__ float wave_reduce_sum(float v) {
    // full 64-lane wave reduction
    for (int off = 32; off > 0; off >>= 1)
        v += __shfl_down(v, off, 64);
    return v;
}

__global__ void __launch_bounds__(256) fused_kernel(
        const float* __restrict__ y, const float* __restrict__ mu,
        const float* __restrict__ sd, const int* __restrict__ idx,
        float* __restrict__ q, float* __restrict__ out) {
    const int i = blockIdx.x;   // sample
    const int t = threadIdx.x;
    const int wave = t >> 6;
    const int lane = t & 63;

    // ---- phase 1: per-sample chi-square sum ----
    float term = 0.0f;
    if (t < KDOF) {
        const int id = idx[i * KDOF + t];
        const float d = (y[id] - mu[id]) / sd[id];
        term = d * d;
    }
    term = wave_reduce_sum(term);
    __shared__ float partial[4];
    if (lane == 0) partial[wave] = term;
    __syncthreads();
    // waves 2,3 contribute +0.0f -> bitwise identical to the 2-wave version
    if (t == 0) q[i] = ((partial[0] + partial[1]) + partial[2]) + partial[3];

    // ---- grid-wide barrier (handles cross-XCD visibility of q) ----
    cg::this_grid().sync();

    if (i != 0) return;

    // ---- phase 2: finalize (identical numerics to previous finalize_kernel) ----
    __shared__ float lds[4];
    __shared__ float s_mean;

    const float v = (t < NUM_SAMPLES) ? q[t] : 0.0f;

    // pass 1: sum -> mean
    float s = wave_reduce_sum(v);
    if (lane == 0) lds[wave] = s;
    __syncthreads();
    if (t == 0) {
        float tot = lds[0] + lds[1] + lds[2] + lds[3];
        s_mean = tot / (float)NUM_SAMPLES;
    }
    __syncthreads();
    const float mean = s_mean;

    // pass 2: sum of squared deviations (two-pass variance, ddof=1)
    const float d2 = (t < NUM_SAMPLES) ? (v - mean) : 0.0f;
    float ss = wave_reduce_sum(d2 * d2);
    __syncthreads();  // reuse lds safely
    if (lane == 0) lds[wave] = ss;
    __syncthreads();
    if (t == 0) {
        const float ssd = lds[0] + lds[1] + lds[2] + lds[3];
        const float var = ssd / (float)(NUM_SAMPLES - 1);
        const float k = (float)KDOF;
        const float two_k = 2.0f * k;
        const float dm = mean - k;
        const float kl = 0.5f * logf(two_k / var) + (var + dm * dm) / (2.0f * two_k) - 0.5f;
        out[0] = kl;
    }
}

extern "C" void kernel_launch(void* const* d_in, const int* in_sizes, int n_in,
                              void* d_out, int out_size, void* d_ws, size_t ws_size,
                              hipStream_t stream) {
    const float* y   = (const float*)d_in[0];
    const float* mu  = (const float*)d_in[1];
    const float* sd  = (const float*)d_in[2];
    const int*   idx = (const int*)d_in[3];
    float* out = (float*)d_out;
    float* q   = (float*)d_ws;  // 200 floats of scratch; fully written each call

    void* args[] = { (void*)&y, (void*)&mu, (void*)&sd, (void*)&idx,
                     (void*)&q, (void*)&out };
    hipLaunchCooperativeKernel(reinterpret_cast<void*>(fused_kernel),
                               dim3(NUM_SAMPLES), dim3(256), args, 0, stream);
}

// Round 3
// 149.738 us; speedup vs baseline: 1.2468x; 1.2468x over previous
//
#include <hip/hip_runtime.h>
#include <hip/hip_bf16.h>
#include <math.h>

// Problem: TOTAL=16M fp32 y/mu/std; idx int32 [200,100].
// q[i] = sum_j ((y[idx]-mu[idx])/std[idx])^2 ; out = KL(N(mean(q),var(q,ddof=1)) || N(K, 2K)).
// Latency-bound random-gather + tiny reduction. Two kernels:
//   k1: 200 blocks x 128 thr -> q[i] into d_ws
//   k2: 1 block x 256 thr -> two-pass mean/var -> KL scalar
//
// R1 post-mortem: hipLaunchCooperativeKernel fusion REGRESSED 149.8 -> 186.7 us
// (cooperative dispatch path + graph-capture interaction costs ~37 us; grid.sync
// serializes all blocks). Reverted to the two-dispatch structure. The timed
// iteration is dominated by harness re-poison fills (~40 us each, 83% HBM peak);
// our two dispatches are ~8-10 us of the 149 us total.
// R2 was an infra failure (container acquisition), not a kernel failure;
// resubmitting the same known-good source.

#define NUM_SAMPLES 200
#define KDOF 100

__device__ __forceinline__ float wave_reduce_sum(float v) {
    // full 64-lane wave reduction
    for (int off = 32; off > 0; off >>= 1)
        v += __shfl_down(v, off, 64);
    return v;
}

__global__ void __launch_bounds__(128) compute_q_kernel(
        const float* __restrict__ y, const float* __restrict__ mu,
        const float* __restrict__ sd, const int* __restrict__ idx,
        float* __restrict__ q) {
    const int i = blockIdx.x;   // sample
    const int j = threadIdx.x;  // dof lane
    float term = 0.0f;
    if (j < KDOF) {
        const int id = idx[i * KDOF + j];
        const float d = (y[id] - mu[id]) / sd[id];
        term = d * d;
    }
    term = wave_reduce_sum(term);
    __shared__ float partial[2];
    const int wave = j >> 6;
    if ((j & 63) == 0) partial[wave] = term;
    __syncthreads();
    if (j == 0) q[i] = partial[0] + partial[1];
}

__global__ void __launch_bounds__(256) finalize_kernel(
        const float* __restrict__ q, float* __restrict__ out) {
    const int t = threadIdx.x;
    const int wave = t >> 6;
    const int lane = t & 63;
    __shared__ float lds[4];
    __shared__ float s_mean;

    const float v = (t < NUM_SAMPLES) ? q[t] : 0.0f;

    // ---- pass 1: sum -> mean ----
    float s = wave_reduce_sum(v);
    if (lane == 0) lds[wave] = s;
    __syncthreads();
    if (t == 0) {
        float tot = lds[0] + lds[1] + lds[2] + lds[3];
        s_mean = tot / (float)NUM_SAMPLES;
    }
    __syncthreads();
    const float mean = s_mean;

    // ---- pass 2: sum of squared deviations (two-pass variance, ddof=1) ----
    const float d = (t < NUM_SAMPLES) ? (v - mean) : 0.0f;
    float ss = wave_reduce_sum(d * d);
    __syncthreads();  // reuse lds safely
    if (lane == 0) lds[wave] = ss;
    __syncthreads();
    if (t == 0) {
        const float ssd = lds[0] + lds[1] + lds[2] + lds[3];
        const float var = ssd / (float)(NUM_SAMPLES - 1);
        const float k = (float)KDOF;
        const float two_k = 2.0f * k;
        const float dm = mean - k;
        const float kl = 0.5f * logf(two_k / var) + (var + dm * dm) / (2.0f * two_k) - 0.5f;
        out[0] = kl;
    }
}

extern "C" void kernel_launch(void* const* d_in, const int* in_sizes, int n_in,
                              void* d_out, int out_size, void* d_ws, size_t ws_size,
                              hipStream_t stream) {
    const float* y   = (const float*)d_in[0];
    const float* mu  = (const float*)d_in[1];
    const float* sd  = (const float*)d_in[2];
    const int*   idx = (const int*)d_in[3];
    float* out = (float*)d_out;
    float* q   = (float*)d_ws;  // 200 floats of scratch; fully written each call

    compute_q_kernel<<<NUM_SAMPLES, 128, 0, stream>>>(y, mu, sd, idx, q);
    finalize_kernel<<<1, 256, 0, stream>>>(q, out);
}